// Round 6
// baseline (175.780 us; speedup 1.0000x reference)
//
#include <hip/hip_runtime.h>
#include <math.h>

#define CSTRIDE (512 * 512)

// numpy generic-strided einsum inner loop (scalar C, no SIMD, no FMA):
// accum += c[q]*v[q], q ascending, 64-deep sequential chain, each term
// mul-rounded then add-rounded. REQUIRED bit-exact: feeds rintf() quantization.
__device__ __forceinline__ float chain_dot64_nofma(const float* __restrict__ c,
                                                   const float* __restrict__ v)
{
#pragma clang fp contract(off)
    float s = 0.0f;
#pragma unroll
    for (int q = 0; q < 64; ++q) s = s + c[q] * v[q];
    return s;
}

// Single-arg launch_bounds (R2/R4 evidence: 2nd arg misbehaves on gfx950 —
// "4" capped VGPR at 64 and spilled ~120MB). Natural VGPR ~100 (R4) <= 128
// -> 4 waves/SIMD possible; LDS 40KB -> 4 wg/CU; grid 1024 = 4 tiles/CU
// -> single balanced round (vs R1's 3+1 imbalance = the ~37us stall share).
__global__ __launch_bounds__(256)
void jpeg_kernel(const float* __restrict__ img,
                 const float* __restrict__ rgb2yuv,
                 const float* __restrict__ yuv2rgb,
                 const float* __restrict__ dctC,
                 const float* __restrict__ qlum,
                 const float* __restrict__ qchrom,
                 float* __restrict__ out)
{
#pragma clang fp contract(off)
    // 40KB total:
    //   A    16KB fp32 — staging for forward (per channel), recon for output (per oc)
    //   NYU  16KB — int16 quantized n for Y (lo half) and U (hi half), packed per cell
    //   NW    8KB — int16 quantized n for W
    // n = rintf(d/Q) is an integer |n|<=~205 (|d|<=2048, Q>=10): int16-exact,
    // and dq = (float)n * Q is EXACT (integers, product < 2^24) == rintf(d/Q)*Q.
    __shared__ float A[4096];
    __shared__ int   NYU[4096];
    __shared__ short NW[4096];

    const int tid  = threadIdx.x;
    const int lane = tid & 63;                                        // block index
    const int wv   = tid >> 6;
    const int p0u  = __builtin_amdgcn_readfirstlane(wv * 16);         // wave's p range

    const int b  = blockIdx.x >> 6;
    const int y0 = (blockIdx.x & 63) << 3;
    const size_t base0 = (size_t)b * 3 * CSTRIDE + (size_t)y0 * 512;

    // Inverse-DCT row constants for this wave's two spatial rows x = 2*wv, 2*wv+1.
    // dctC[x*512 + u*8] = M[x][u] * M[0][0]; 1/M[0][0] = 2.828427...
    const int xb = __builtin_amdgcn_readfirstlane(wv * 2);
    float mrow[2][8];
#pragma unroll
    for (int k = 0; k < 2; ++k)
#pragma unroll
        for (int u = 0; u < 8; ++u)
            mrow[k][u] = dctC[(size_t)(xb + k) * 512 + u * 8] * 2.82842712474619f;

    // Column-pass constants (compile-time -> literals):
    // MT[r][c] = 0.5*cos((2c+1)*r*pi/16), row 0 scaled by 1/sqrt(2)
    const float MT[8][8] = {
        { 0.353553391f,  0.353553391f,  0.353553391f,  0.353553391f,  0.353553391f,  0.353553391f,  0.353553391f,  0.353553391f},
        { 0.490392640f,  0.415734806f,  0.277785117f,  0.097545161f, -0.097545161f, -0.277785117f, -0.415734806f, -0.490392640f},
        { 0.461939766f,  0.191341716f, -0.191341716f, -0.461939766f, -0.461939766f, -0.191341716f,  0.191341716f,  0.461939766f},
        { 0.415734806f, -0.097545161f, -0.490392640f, -0.277785117f,  0.277785117f,  0.490392640f,  0.097545161f, -0.415734806f},
        { 0.353553391f, -0.353553391f, -0.353553391f,  0.353553391f,  0.353553391f, -0.353553391f, -0.353553391f,  0.353553391f},
        { 0.277785117f, -0.490392640f,  0.097545161f,  0.415734806f, -0.415734806f, -0.097545161f,  0.490392640f, -0.277785117f},
        { 0.191341716f, -0.461939766f,  0.461939766f, -0.191341716f, -0.191341716f,  0.461939766f, -0.461939766f,  0.191341716f},
        { 0.097545161f, -0.277785117f,  0.415734806f, -0.490392640f,  0.490392640f, -0.415734806f,  0.277785117f, -0.097545161f}};

    // ============ Forward: per channel, stage -> exact DCT -> int16 n ============
    for (int ch = 0; ch < 3; ++ch) {
        const float m0 = rgb2yuv[3 * ch + 0];
        const float m1 = rgb2yuv[3 * ch + 1];
        const float m2 = rgb2yuv[3 * ch + 2];

        // Stage channel ch into A. Passes 2-3 reload img (L2/L3-hot; img is
        // read-only). Color math: EXACT numpy order (no FMA).
#pragma unroll
        for (int i = 0; i < 4; ++i) {
            const size_t f4 = 4 * (size_t)(tid + 256 * i);
            const float4 R4 = *(const float4*)(img + base0 + f4);
            const float4 G4 = *(const float4*)(img + base0 + CSTRIDE + f4);
            const float4 B4 = *(const float4*)(img + base0 + 2 * CSTRIDE + f4);
            const float* rp = (const float*)&R4;
            const float* gp = (const float*)&G4;
            const float* bp = (const float*)&B4;
#pragma unroll
            for (int jj = 0; jj < 4; ++jj) {
                const int flat = 4 * (tid + 256 * i) + jj;   // x*512 + col
                const int w = flat & 511, x = flat >> 9;
                const int idx = ((x << 3) + (w & 7)) * 64 + (w >> 3);
                const float t = (m0 * rp[jj] + m1 * gp[jj]) + m2 * bp[jj];
                A[idx] = t * 255.0f - 128.0f;
            }
        }
        __syncthreads();   // A fully staged

        // preload this thread's block column (64 VGPRs)
        float v[64];
#pragma unroll
        for (int q = 0; q < 64; ++q) v[q] = A[q * 64 + lane];

        // forward DCT: 64-deep sequential no-FMA chain, quantize — EXACT
        const float* qtab = (ch == 0) ? qlum : qchrom;
        short* nyus = (short*)NYU;
        for (int j = 0; j < 16; ++j) {
            const float* Crow = dctC + (size_t)(p0u + j) * 64;  // uniform -> s_load
            const float d  = chain_dot64_nofma(Crow, v);
            const float qv = qtab[p0u + j];
            const short n  = (short)(int)rintf(d / qv);   // fp32 div, half-even
            const int cell = (p0u + j) * 64 + lane;
            if (ch == 0)      nyus[2 * cell]     = n;
            else if (ch == 1) nyus[2 * cell + 1] = n;
            else              NW[cell]           = n;
        }
        __syncthreads();   // preloads done before next stage overwrites A; n visible
    }

    // ============ Inverse: mix dq in coefficient space (linear), IDCT, store ======
    // out_oc = (IDCT(sum_c m_oc,c * dq_c) )/255 + (sum_c m_oc,c)*128/255
    const float s255 = 1.0f / 255.0f;

    for (int oc = 0; oc < 3; ++oc) {
        const float m0 = yuv2rgb[3 * oc + 0];
        const float m1 = yuv2rgb[3 * oc + 1];
        const float m2 = yuv2rgb[3 * oc + 2];
        const float koc = (m0 + m1 + m2) * (128.0f / 255.0f);

        // column pass over u: du = mixed dequant; t[u][y] = sum_q MT[y][q]*du[q]
        float t[64];
#pragma unroll
        for (int u = 0; u < 8; ++u) {
            float du[8];
#pragma unroll
            for (int q = 0; q < 8; ++q) {
                const int cell = (u * 8 + q) * 64 + lane;
                const int pk = NYU[cell];                 // one b32: {nY, nU}
                const float nY = (float)(short)(pk & 0xFFFF);
                const float nU = (float)(short)(pk >> 16);
                const float nWv = (float)NW[cell];
                const float ql = qlum[u * 8 + q];          // uniform s_load
                const float qc = qchrom[u * 8 + q];
                // dq values are exact integers*Q; mix is the linear reorder
                du[q] = fmaf(m0, nY * ql, fmaf(m1, nU * qc, m2 * (nWv * qc)));
            }
#pragma unroll
            for (int y = 0; y < 8; ++y) {
                float s = MT[y][0] * du[0];
#pragma unroll
                for (int q = 1; q < 8; ++q) s = fmaf(MT[y][q], du[q], s);
                t[u * 8 + y] = s;
            }
        }
        __syncthreads();   // previous oc's output reads of A are done

        // row pass: write this wave's 16 recon cells into A
#pragma unroll
        for (int j = 0; j < 16; ++j) {
            const int k = j >> 3, y = j & 7;     // p = p0u+j = (xb+k)*8 + y
            float s = mrow[k][0] * t[y];
#pragma unroll
            for (int u = 1; u < 8; ++u) s = fmaf(mrow[k][u], t[u * 8 + y], s);
            A[(p0u + j) * 64 + lane] = s;
        }
        __syncthreads();   // recon visible

        // output channel oc: folded affine, coalesced float4 stores
#pragma unroll
        for (int i = 0; i < 4; ++i) {
            float4 o;
            float* qo = (float*)&o;
#pragma unroll
            for (int jj = 0; jj < 4; ++jj) {
                const int flat = 4 * (tid + 256 * i) + jj;
                const int w = flat & 511, x = flat >> 9;
                const int cell = ((x << 3) + (w & 7)) * 64 + (w >> 3);  // 2-way (free)
                qo[jj] = fmaf(A[cell], s255, koc);
            }
            const size_t f4 = 4 * (size_t)(tid + 256 * i);
            *(float4*)(out + base0 + (size_t)oc * CSTRIDE + f4) = o;
        }
        // next oc's column pass reads only NYU/NW (not A); the barrier before
        // its A-writes covers these output reads.
    }
}

extern "C" void kernel_launch(void* const* d_in, const int* in_sizes, int n_in,
                              void* d_out, int out_size, void* d_ws, size_t ws_size,
                              hipStream_t stream) {
    const float* img = (const float*)d_in[0];
    const float* r2y = (const float*)d_in[1];
    const float* y2r = (const float*)d_in[2];
    const float* C   = (const float*)d_in[3];
    const float* ql  = (const float*)d_in[4];
    const float* qc  = (const float*)d_in[5];
    float* o = (float*)d_out;

    jpeg_kernel<<<dim3(16 * 64), dim3(256), 0, stream>>>(img, r2y, y2r, C, ql, qc, o);
}

// Round 7
// 161.908 us; speedup vs baseline: 1.0857x; 1.0857x over previous
//
#include <hip/hip_runtime.h>
#include <math.h>

#define CSTRIDE (512 * 512)
#define NTILES  1024
#define GRID    768   // 3 blocks/CU x 256 CU = exact residency at 48KB LDS

// numpy generic-strided einsum inner loop (scalar C, no SIMD, no FMA):
// accum += c[q]*v[q], q ascending, 64-deep sequential chain, each term
// mul-rounded then add-rounded. REQUIRED bit-exact: feeds rintf() quantization.
__device__ __forceinline__ float chain_dot64_nofma(const float* __restrict__ c,
                                                   const float* __restrict__ v)
{
#pragma clang fp contract(off)
    float s = 0.0f;
#pragma unroll
    for (int q = 0; q < 64; ++q) s = s + c[q] * v[q];
    return s;
}

// R1 kernel (79us known-good) wrapped in a persistent work-stealing loop.
// Rationale (R1..R6 ledger): VALU issue is pinned at ~42us across all
// instruction-level variants; the remaining ~37us is round-quantization
// (grid 4/CU vs residency 3/CU -> last round runs at 1/3 width). Stealing
// tiles 768..1023 removes the quantization without touching the math.
__global__ __launch_bounds__(256, 3)
void jpeg_kernel(const float* __restrict__ img,
                 const float* __restrict__ rgb2yuv,
                 const float* __restrict__ yuv2rgb,
                 const float* __restrict__ dctC,
                 const float* __restrict__ qlum,
                 const float* __restrict__ qchrom,
                 float* __restrict__ out,
                 unsigned int* __restrict__ counter)
{
#pragma clang fp contract(off)
    __shared__ float V[3][4096];   // 48 KB: per-channel (q=x*8+y)[64] x block[64]
    __shared__ int nextT;

    const int tid  = threadIdx.x;
    const int lane = tid & 63;                                        // block index
    const int wv   = tid >> 6;
    const int p0u  = __builtin_amdgcn_readfirstlane(wv * 16);         // wave's p range

    // ---- tile-independent constants, hoisted out of the persistent loop ----
    const float r00 = rgb2yuv[0], r01 = rgb2yuv[1], r02 = rgb2yuv[2];
    const float r10 = rgb2yuv[3], r11 = rgb2yuv[4], r12 = rgb2yuv[5];
    const float r20 = rgb2yuv[6], r21 = rgb2yuv[7], r22 = rgb2yuv[8];

    // Inverse-DCT row constants for this wave's two spatial rows x = 2*wv, 2*wv+1.
    // dctC[x*512 + u*8] = M[x][u] * M[0][0]; 1/M[0][0] = 2.828427...
    const int xb = __builtin_amdgcn_readfirstlane(wv * 2);
    float mrow[2][8];
#pragma unroll
    for (int k = 0; k < 2; ++k)
#pragma unroll
        for (int u = 0; u < 8; ++u)
            mrow[k][u] = dctC[(size_t)(xb + k) * 512 + u * 8] * 2.82842712474619f;

    // Column-pass constants (compile-time -> folds to literals):
    // MT[r][c] = 0.5*cos((2c+1)*r*pi/16), row 0 scaled by 1/sqrt(2)
    const float MT[8][8] = {
        { 0.353553391f,  0.353553391f,  0.353553391f,  0.353553391f,  0.353553391f,  0.353553391f,  0.353553391f,  0.353553391f},
        { 0.490392640f,  0.415734806f,  0.277785117f,  0.097545161f, -0.097545161f, -0.277785117f, -0.415734806f, -0.490392640f},
        { 0.461939766f,  0.191341716f, -0.191341716f, -0.461939766f, -0.461939766f, -0.191341716f,  0.191341716f,  0.461939766f},
        { 0.415734806f, -0.097545161f, -0.490392640f, -0.277785117f,  0.277785117f,  0.490392640f,  0.097545161f, -0.415734806f},
        { 0.353553391f, -0.353553391f, -0.353553391f,  0.353553391f,  0.353553391f, -0.353553391f, -0.353553391f,  0.353553391f},
        { 0.277785117f, -0.490392640f,  0.097545161f,  0.415734806f, -0.415734806f, -0.097545161f,  0.490392640f, -0.277785117f},
        { 0.191341716f, -0.461939766f,  0.461939766f, -0.191341716f, -0.191341716f,  0.461939766f, -0.461939766f,  0.191341716f},
        { 0.097545161f, -0.277785117f,  0.415734806f, -0.490392640f,  0.490392640f, -0.415734806f,  0.277785117f, -0.097545161f}};

    // Output-stage constants (inverse side: order-insensitive folding)
    const float s255 = 1.0f / 255.0f;
    const float c00 = yuv2rgb[0] * s255, c01 = yuv2rgb[1] * s255, c02 = yuv2rgb[2] * s255;
    const float c10 = yuv2rgb[3] * s255, c11 = yuv2rgb[4] * s255, c12 = yuv2rgb[5] * s255;
    const float c20 = yuv2rgb[6] * s255, c21 = yuv2rgb[7] * s255, c22 = yuv2rgb[8] * s255;
    const float k0 = (yuv2rgb[0] + yuv2rgb[1] + yuv2rgb[2]) * (128.0f / 255.0f);
    const float k1 = (yuv2rgb[3] + yuv2rgb[4] + yuv2rgb[5]) * (128.0f / 255.0f);
    const float k2 = (yuv2rgb[6] + yuv2rgb[7] + yuv2rgb[8]) * (128.0f / 255.0f);

    int tile = blockIdx.x;

    while (true) {
        const int b  = tile >> 6;
        const int y0 = (tile & 63) << 3;
        const size_t base0 = (size_t)b * 3 * CSTRIDE + (size_t)y0 * 512;

        // Phase 1: coalesced RGB loads; numpy color loop model (no FMA) — EXACT
#pragma unroll
        for (int i = 0; i < 4; ++i) {
            const size_t f4 = 4 * (size_t)(tid + 256 * i);
            const float4 R4 = *(const float4*)(img + base0 + f4);
            const float4 G4 = *(const float4*)(img + base0 + CSTRIDE + f4);
            const float4 B4 = *(const float4*)(img + base0 + 2 * CSTRIDE + f4);
            const float* rp = (const float*)&R4;
            const float* gp = (const float*)&G4;
            const float* bp = (const float*)&B4;
#pragma unroll
            for (int jj = 0; jj < 4; ++jj) {
                const int flat = 4 * (tid + 256 * i) + jj;   // x*512 + col
                const int w = flat & 511, x = flat >> 9;
                const int idx = ((x << 3) + (w & 7)) * 64 + (w >> 3);
                const float r_ = rp[jj], g_ = gp[jj], b_ = bp[jj];
                float t;
                t = (r00 * r_ + r01 * g_) + r02 * b_;  V[0][idx] = t * 255.0f - 128.0f;
                t = (r10 * r_ + r11 * g_) + r12 * b_;  V[1][idx] = t * 255.0f - 128.0f;
                t = (r20 * r_ + r21 * g_) + r22 * b_;  V[2][idx] = t * 255.0f - 128.0f;
            }
        }
        __syncthreads();

        for (int c = 0; c < 3; ++c) {
            float* Vc = V[c];

            // preload this thread's block column (64 VGPRs)
            float v[64];
#pragma unroll
            for (int q = 0; q < 64; ++q) v[q] = Vc[q * 64 + lane];
            __syncthreads();   // all waves preloaded before we overwrite Vc

            // forward DCT: 64-deep sequential no-FMA chain, quantize/dequant — EXACT
            const float* qtab = (c == 0) ? qlum : qchrom;
            for (int j = 0; j < 16; ++j) {
                const float* Crow = dctC + (size_t)(p0u + j) * 64;  // uniform -> s_load
                const float d  = chain_dot64_nofma(Crow, v);
                const float qv = qtab[p0u + j];
                const float dq = rintf(d / qv) * qv;   // fp32 div, half-even, fp32 mul
                Vc[(p0u + j) * 64 + lane] = dq;
            }
            __syncthreads();   // dq visible for cross-wave du reads

            // Inverse DCT, separable + FMA (numerically free past quantization):
            //   t[u][y] = sum_v MT[y][v]*d[u][v];  r[x][y] = sum_u M[x][u]*t[u][y]
            float t[64];
#pragma unroll
            for (int u = 0; u < 8; ++u) {
                float du[8];
#pragma unroll
                for (int q = 0; q < 8; ++q) du[q] = Vc[(u * 8 + q) * 64 + lane];
#pragma unroll
                for (int y = 0; y < 8; ++y) {
                    float s = MT[y][0] * du[0];
#pragma unroll
                    for (int q = 1; q < 8; ++q) s = fmaf(MT[y][q], du[q], s);
                    t[u * 8 + y] = s;
                }
            }
            __syncthreads();   // everyone done reading Vc before recon overwrite

#pragma unroll
            for (int j = 0; j < 16; ++j) {
                const int k = j >> 3, y = j & 7;     // p = p0u+j = (xb+k)*8 + y
                float s = mrow[k][0] * t[y];
#pragma unroll
                for (int u = 1; u < 8; ++u) s = fmaf(mrow[k][u], t[u * 8 + y], s);
                Vc[(p0u + j) * 64 + lane] = s;
            }
        }
        __syncthreads();

        // Output: fold yuv2rgb and (x+128)/255 into 3 FMAs per pixel-channel
#pragma unroll
        for (int i = 0; i < 4; ++i) {
            float4 o0, o1, o2;
            float* q0 = (float*)&o0; float* q1 = (float*)&o1; float* q2 = (float*)&o2;
#pragma unroll
            for (int jj = 0; jj < 4; ++jj) {
                const int flat = 4 * (tid + 256 * i) + jj;
                const int w = flat & 511, x = flat >> 9;
                const int cell = ((x << 3) + (w & 7)) * 64 + (w >> 3);  // 2-way (free)
                const float Yv = V[0][cell], Uv = V[1][cell], Wv = V[2][cell];
                q0[jj] = fmaf(c00, Yv, fmaf(c01, Uv, fmaf(c02, Wv, k0)));
                q1[jj] = fmaf(c10, Yv, fmaf(c11, Uv, fmaf(c12, Wv, k1)));
                q2[jj] = fmaf(c20, Yv, fmaf(c21, Uv, fmaf(c22, Wv, k2)));
            }
            const size_t f4 = 4 * (size_t)(tid + 256 * i);
            *(float4*)(out + base0 + f4)                = o0;
            *(float4*)(out + base0 + CSTRIDE + f4)      = o1;
            *(float4*)(out + base0 + 2 * CSTRIDE + f4)  = o2;
        }

        // ---- steal next tile ----
        __syncthreads();   // all V reads done before next tile's restage
        if (tid == 0) nextT = GRID + (int)atomicAdd(counter, 1u);
        __syncthreads();
        tile = nextT;
        if (tile >= NTILES) break;   // wave-uniform exit
    }
}

// Fallback (no workspace): exact R1 behavior, static grid = 1024.
__global__ __launch_bounds__(256, 3)
void jpeg_kernel_static(const float* __restrict__ img,
                        const float* __restrict__ rgb2yuv,
                        const float* __restrict__ yuv2rgb,
                        const float* __restrict__ dctC,
                        const float* __restrict__ qlum,
                        const float* __restrict__ qchrom,
                        float* __restrict__ out)
{
#pragma clang fp contract(off)
    __shared__ float V[3][4096];

    const int tid  = threadIdx.x;
    const int lane = tid & 63;
    const int wv   = tid >> 6;
    const int p0u  = __builtin_amdgcn_readfirstlane(wv * 16);

    const int b  = blockIdx.x >> 6;
    const int y0 = (blockIdx.x & 63) << 3;
    const size_t base0 = (size_t)b * 3 * CSTRIDE + (size_t)y0 * 512;

    const float r00 = rgb2yuv[0], r01 = rgb2yuv[1], r02 = rgb2yuv[2];
    const float r10 = rgb2yuv[3], r11 = rgb2yuv[4], r12 = rgb2yuv[5];
    const float r20 = rgb2yuv[6], r21 = rgb2yuv[7], r22 = rgb2yuv[8];

#pragma unroll
    for (int i = 0; i < 4; ++i) {
        const size_t f4 = 4 * (size_t)(tid + 256 * i);
        const float4 R4 = *(const float4*)(img + base0 + f4);
        const float4 G4 = *(const float4*)(img + base0 + CSTRIDE + f4);
        const float4 B4 = *(const float4*)(img + base0 + 2 * CSTRIDE + f4);
        const float* rp = (const float*)&R4;
        const float* gp = (const float*)&G4;
        const float* bp = (const float*)&B4;
#pragma unroll
        for (int jj = 0; jj < 4; ++jj) {
            const int flat = 4 * (tid + 256 * i) + jj;
            const int w = flat & 511, x = flat >> 9;
            const int idx = ((x << 3) + (w & 7)) * 64 + (w >> 3);
            const float r_ = rp[jj], g_ = gp[jj], b_ = bp[jj];
            float t;
            t = (r00 * r_ + r01 * g_) + r02 * b_;  V[0][idx] = t * 255.0f - 128.0f;
            t = (r10 * r_ + r11 * g_) + r12 * b_;  V[1][idx] = t * 255.0f - 128.0f;
            t = (r20 * r_ + r21 * g_) + r22 * b_;  V[2][idx] = t * 255.0f - 128.0f;
        }
    }
    __syncthreads();

    const int xb = __builtin_amdgcn_readfirstlane(wv * 2);
    float mrow[2][8];
#pragma unroll
    for (int k = 0; k < 2; ++k)
#pragma unroll
        for (int u = 0; u < 8; ++u)
            mrow[k][u] = dctC[(size_t)(xb + k) * 512 + u * 8] * 2.82842712474619f;

    const float MT[8][8] = {
        { 0.353553391f,  0.353553391f,  0.353553391f,  0.353553391f,  0.353553391f,  0.353553391f,  0.353553391f,  0.353553391f},
        { 0.490392640f,  0.415734806f,  0.277785117f,  0.097545161f, -0.097545161f, -0.277785117f, -0.415734806f, -0.490392640f},
        { 0.461939766f,  0.191341716f, -0.191341716f, -0.461939766f, -0.461939766f, -0.191341716f,  0.191341716f,  0.461939766f},
        { 0.415734806f, -0.097545161f, -0.490392640f, -0.277785117f,  0.277785117f,  0.490392640f,  0.097545161f, -0.415734806f},
        { 0.353553391f, -0.353553391f, -0.353553391f,  0.353553391f,  0.353553391f, -0.353553391f, -0.353553391f,  0.353553391f},
        { 0.277785117f, -0.490392640f,  0.097545161f,  0.415734806f, -0.415734806f, -0.097545161f,  0.490392640f, -0.277785117f},
        { 0.191341716f, -0.461939766f,  0.461939766f, -0.191341716f, -0.191341716f,  0.461939766f, -0.461939766f,  0.191341716f},
        { 0.097545161f, -0.277785117f,  0.415734806f, -0.490392640f,  0.490392640f, -0.415734806f,  0.277785117f, -0.097545161f}};

    for (int c = 0; c < 3; ++c) {
        float* Vc = V[c];
        float v[64];
#pragma unroll
        for (int q = 0; q < 64; ++q) v[q] = Vc[q * 64 + lane];
        __syncthreads();

        const float* qtab = (c == 0) ? qlum : qchrom;
        for (int j = 0; j < 16; ++j) {
            const float* Crow = dctC + (size_t)(p0u + j) * 64;
            const float d  = chain_dot64_nofma(Crow, v);
            const float qv = qtab[p0u + j];
            const float dq = rintf(d / qv) * qv;
            Vc[(p0u + j) * 64 + lane] = dq;
        }
        __syncthreads();

        float t[64];
#pragma unroll
        for (int u = 0; u < 8; ++u) {
            float du[8];
#pragma unroll
            for (int q = 0; q < 8; ++q) du[q] = Vc[(u * 8 + q) * 64 + lane];
#pragma unroll
            for (int y = 0; y < 8; ++y) {
                float s = MT[y][0] * du[0];
#pragma unroll
                for (int q = 1; q < 8; ++q) s = fmaf(MT[y][q], du[q], s);
                t[u * 8 + y] = s;
            }
        }
        __syncthreads();

#pragma unroll
        for (int j = 0; j < 16; ++j) {
            const int k = j >> 3, y = j & 7;
            float s = mrow[k][0] * t[y];
#pragma unroll
            for (int u = 1; u < 8; ++u) s = fmaf(mrow[k][u], t[u * 8 + y], s);
            Vc[(p0u + j) * 64 + lane] = s;
        }
    }
    __syncthreads();

    const float s255 = 1.0f / 255.0f;
    const float c00 = yuv2rgb[0] * s255, c01 = yuv2rgb[1] * s255, c02 = yuv2rgb[2] * s255;
    const float c10 = yuv2rgb[3] * s255, c11 = yuv2rgb[4] * s255, c12 = yuv2rgb[5] * s255;
    const float c20 = yuv2rgb[6] * s255, c21 = yuv2rgb[7] * s255, c22 = yuv2rgb[8] * s255;
    const float k0 = (yuv2rgb[0] + yuv2rgb[1] + yuv2rgb[2]) * (128.0f / 255.0f);
    const float k1 = (yuv2rgb[3] + yuv2rgb[4] + yuv2rgb[5]) * (128.0f / 255.0f);
    const float k2 = (yuv2rgb[6] + yuv2rgb[7] + yuv2rgb[8]) * (128.0f / 255.0f);

#pragma unroll
    for (int i = 0; i < 4; ++i) {
        float4 o0, o1, o2;
        float* q0 = (float*)&o0; float* q1 = (float*)&o1; float* q2 = (float*)&o2;
#pragma unroll
        for (int jj = 0; jj < 4; ++jj) {
            const int flat = 4 * (tid + 256 * i) + jj;
            const int w = flat & 511, x = flat >> 9;
            const int cell = ((x << 3) + (w & 7)) * 64 + (w >> 3);
            const float Yv = V[0][cell], Uv = V[1][cell], Wv = V[2][cell];
            q0[jj] = fmaf(c00, Yv, fmaf(c01, Uv, fmaf(c02, Wv, k0)));
            q1[jj] = fmaf(c10, Yv, fmaf(c11, Uv, fmaf(c12, Wv, k1)));
            q2[jj] = fmaf(c20, Yv, fmaf(c21, Uv, fmaf(c22, Wv, k2)));
        }
        const size_t f4 = 4 * (size_t)(tid + 256 * i);
        *(float4*)(out + base0 + f4)                = o0;
        *(float4*)(out + base0 + CSTRIDE + f4)      = o1;
        *(float4*)(out + base0 + 2 * CSTRIDE + f4)  = o2;
    }
}

extern "C" void kernel_launch(void* const* d_in, const int* in_sizes, int n_in,
                              void* d_out, int out_size, void* d_ws, size_t ws_size,
                              hipStream_t stream) {
    const float* img = (const float*)d_in[0];
    const float* r2y = (const float*)d_in[1];
    const float* y2r = (const float*)d_in[2];
    const float* C   = (const float*)d_in[3];
    const float* ql  = (const float*)d_in[4];
    const float* qc  = (const float*)d_in[5];
    float* o = (float*)d_out;

    if (ws_size >= sizeof(unsigned int)) {
        unsigned int* cnt = (unsigned int*)d_ws;
        hipMemsetAsync(cnt, 0, sizeof(unsigned int), stream);
        jpeg_kernel<<<dim3(GRID), dim3(256), 0, stream>>>(img, r2y, y2r, C, ql, qc, o, cnt);
    } else {
        jpeg_kernel_static<<<dim3(NTILES), dim3(256), 0, stream>>>(img, r2y, y2r, C, ql, qc, o);
    }
}